// Round 7
// baseline (346.657 us; speedup 1.0000x reference)
//
#include <hip/hip_runtime.h>

#define NN 50000
#define EE 800000
#define INC 512
#define HIDC 128
#define OUTC 256
#define CAP 64
#define OV_CAP 65536
#define BUILD_BLOCKS 3125     // EE / 256 exactly: 1 thread per edge
#define GB1 782               // ceil(NN/64)

typedef __attribute__((ext_vector_type(8))) short bf16x8;
typedef __attribute__((ext_vector_type(4))) float f32x4;

__device__ __forceinline__ short f2bf(float f) {
    unsigned u = __float_as_uint(f);
    unsigned r = u + 0x7fff + ((u >> 16) & 1);   // RNE to bf16
    return (short)(r >> 16);
}
__device__ __forceinline__ float bf2f(short s) {
    return __uint_as_float(((unsigned)(unsigned short)s) << 16);
}

// ---------------------------------------------------------------------------
// GEMM core: C[M,Nc] = A[M,K] * B[Nc,K]^T (+bias). BM=64, BN=128, BK=64.
// 256 threads = 4 waves; wave computes 32x64 (2x4 tiles of 16x16x32 MFMA).
// A fp32 (converted during staging) or bf16; B fp32 (w1/w2). Verified layouts:
// A-frag A[m=lane&15][k=quad*8+j]; C/D col=lane&15, row=quad*4+reg.
template<bool IN_BF16, bool ADDBIAS, bool OUT_BF16>
__device__ __forceinline__ void gemm_core(
    const void* __restrict__ Av, const float* __restrict__ B,
    const float* __restrict__ bias, void* __restrict__ Cv,
    int M, int Nc, int K, int bx, int by,
    short As[64][72], short Bs[128][72])
{
    int tid = threadIdx.x;
    int lane = tid & 63, wave = tid >> 6;
    int row0 = bx * 64, col0 = by * 128;
    int wm = (wave & 1) * 32, wn = (wave >> 1) * 64;
    int l16 = lane & 15, quad = lane >> 4;

    f32x4 acc[2][4];
#pragma unroll
    for (int i = 0; i < 2; i++)
#pragma unroll
        for (int j = 0; j < 4; j++) acc[i][j] = {0.f, 0.f, 0.f, 0.f};

    for (int k0 = 0; k0 < K; k0 += 64) {
        // ---- stage A tile 64x64 ----
        if (IN_BF16) {
            const short* A = (const short*)Av;
#pragma unroll
            for (int w = 0; w < 2; w++) {
                int f = tid + w * 256;          // 512 x 16B slots
                int rr = f >> 3, c8 = f & 7;
                int gr = row0 + rr;
                bf16x8 v = {0, 0, 0, 0, 0, 0, 0, 0};
                if (gr < M) v = *(const bf16x8*)&A[(long)gr * K + k0 + c8 * 8];
                *(bf16x8*)&As[rr][c8 * 8] = v;
            }
        } else {
            const float* A = (const float*)Av;
#pragma unroll
            for (int w = 0; w < 4; w++) {
                int f = tid + w * 256;          // 1024 x float4 slots
                int rr = f >> 4, c4 = f & 15;
                int gr = row0 + rr;
                float4 v = make_float4(0.f, 0.f, 0.f, 0.f);
                if (gr < M) v = *(const float4*)&A[(long)gr * K + k0 + c4 * 4];
                short4 s;
                s.x = f2bf(v.x); s.y = f2bf(v.y); s.z = f2bf(v.z); s.w = f2bf(v.w);
                *(short4*)&As[rr][c4 * 4] = s;
            }
        }
        // ---- stage B tile 128x64 (fp32 -> bf16) ----
#pragma unroll
        for (int w = 0; w < 8; w++) {
            int f = tid + w * 256;              // 2048 x float4 slots
            int rr = f >> 4, c4 = f & 15;
            float4 v = *(const float4*)&B[(long)(col0 + rr) * K + k0 + c4 * 4];
            short4 s;
            s.x = f2bf(v.x); s.y = f2bf(v.y); s.z = f2bf(v.z); s.w = f2bf(v.w);
            *(short4*)&Bs[rr][c4 * 4] = s;
        }
        __syncthreads();

#pragma unroll
        for (int kk = 0; kk < 64; kk += 32) {
            bf16x8 af[2], bfr[4];
#pragma unroll
            for (int i = 0; i < 2; i++)
                af[i] = *(const bf16x8*)&As[wm + i * 16 + l16][kk + quad * 8];
#pragma unroll
            for (int j = 0; j < 4; j++)
                bfr[j] = *(const bf16x8*)&Bs[wn + j * 16 + l16][kk + quad * 8];
#pragma unroll
            for (int i = 0; i < 2; i++)
#pragma unroll
                for (int j = 0; j < 4; j++)
                    acc[i][j] = __builtin_amdgcn_mfma_f32_16x16x32_bf16(
                        af[i], bfr[j], acc[i][j], 0, 0, 0);
        }
        __syncthreads();
    }

    // ---- epilogue ----
#pragma unroll
    for (int i = 0; i < 2; i++) {
#pragma unroll
        for (int rr = 0; rr < 4; rr++) {
            int grow = row0 + wm + i * 16 + quad * 4 + rr;
            if (grow < M) {
#pragma unroll
                for (int j = 0; j < 4; j++) {
                    int gcol = col0 + wn + j * 16 + l16;
                    float v = acc[i][j][rr];
                    if (ADDBIAS) v += bias[gcol];
                    if (OUT_BF16)
                        ((short*)Cv)[(long)grow * Nc + gcol] = f2bf(v);
                    else
                        ((float*)Cv)[(long)grow * Nc + gcol] = v;
                }
            }
        }
    }
}

// ---------------------------------------------------------------------------
// Fat kernel: blocks [0,BUILD_BLOCKS) build dst-buckets with ONE EDGE PER
// THREAD (was 16 sequential atomic->store chains per thread; that left the
// machine latency-bound: MfmaUtil 2.7%/VALUBusy 8.4%/HBM 16% all idle while
// 50K threads ground 16-deep serial atomic round trips). 800K threads x one
// atomicAdd each maximizes outstanding-atomic concurrency; a wave issues 64
// atomics in one instruction. The remaining blocks run gemm1.
__global__ __launch_bounds__(256) void fat_build_gemm1(
    const int* __restrict__ ei, int* __restrict__ cnt,
    unsigned short* __restrict__ bucket, int* __restrict__ ovcnt,
    int* __restrict__ ovlist,
    const float* __restrict__ x, const float* __restrict__ w1,
    short* __restrict__ h)
{
    __shared__ short As[64][72];
    __shared__ short Bs[128][72];

    if (blockIdx.x < BUILD_BLOCKS) {
        int e = blockIdx.x * 256 + threadIdx.x;     // < EE (3125*256 == EE)
        int src = ei[e];
        int dst = ei[EE + e];
        int pos = atomicAdd(&cnt[dst], 1);
        if (pos < CAP) {
            bucket[(long)dst * CAP + pos] = (unsigned short)src;
        } else {
            int o = atomicAdd(ovcnt, 1);
            if (o < OV_CAP) { ovlist[o * 2] = src; ovlist[o * 2 + 1] = dst; }
        }
    } else {
        gemm_core<false, false, true>(x, w1, nullptr, h, NN, HIDC, INC,
                                      blockIdx.x - BUILD_BLOCKS, 0, As, Bs);
    }
}

// out = r2 @ w2^T + b2 (A already bf16)
__global__ __launch_bounds__(256) void gemm2_k(
    const short* __restrict__ r2, const float* __restrict__ w2,
    const float* __restrict__ b2, float* __restrict__ out)
{
    __shared__ short As[64][72];
    __shared__ short Bs[128][72];
    gemm_core<true, true, false>(r2, w2, b2, out, NN, OUTC, HIDC,
                                 blockIdx.x, blockIdx.y, As, Bs);
}

// ---------------------------------------------------------------------------
// Gather: out_row[n] = sum_{e->n} hsrc[src_e] (fp32 acc). 16 lanes/node,
// 16B loads/lane, 8 row-loads in flight (measured neutral vs 4; kept).
// RELU: writes bf16 relu(sum+bias); else bf16 raw sum.
template<bool RELU>
__global__ __launch_bounds__(256) void gather_k(
    const short* __restrict__ hsrc, const unsigned short* __restrict__ bucket,
    const int* __restrict__ cnt, const float* __restrict__ bias,
    short* __restrict__ rout)
{
    int t = threadIdx.x;
    int node = blockIdx.x * 16 + (t >> 4);
    int c8 = t & 15;
    if (node >= NN) return;
    int m = cnt[node]; if (m > CAP) m = CAP;
    const unsigned short* bk = bucket + (long)node * CAP;
    float acc[8];
#pragma unroll
    for (int k = 0; k < 8; k++) acc[k] = 0.f;
    int j = 0;
    for (; j + 8 <= m; j += 8) {
        int s[8];
#pragma unroll
        for (int q = 0; q < 8; q++) s[q] = bk[j + q];
        bf16x8 v[8];
#pragma unroll
        for (int q = 0; q < 8; q++)
            v[q] = *(const bf16x8*)&hsrc[((long)s[q] << 7) + c8 * 8];
#pragma unroll
        for (int q = 0; q < 8; q++)
#pragma unroll
            for (int k = 0; k < 8; k++) acc[k] += bf2f(v[q][k]);
    }
    for (; j < m; j++) {
        int s0 = bk[j];
        bf16x8 v0 = *(const bf16x8*)&hsrc[((long)s0 << 7) + c8 * 8];
#pragma unroll
        for (int k = 0; k < 8; k++) acc[k] += bf2f(v0[k]);
    }
    bf16x8 o;
    if (RELU) {
#pragma unroll
        for (int k = 0; k < 8; k++)
            o[k] = f2bf(fmaxf(acc[k] + bias[c8 * 8 + k], 0.f));
    } else {
#pragma unroll
        for (int k = 0; k < 8; k++) o[k] = f2bf(acc[k]);
    }
    *(bf16x8*)&rout[((long)node << 7) + c8 * 8] = o;
}

// ---------------------------------------------------------------------------
// Overflow fixups (single block, expected n==0). Exactness preserved.
// ovfix1 recomputes overflow nodes' full sums from h (no agg buffer).
__global__ __launch_bounds__(128) void ovfix1_k(
    const short* __restrict__ h, const float* __restrict__ b1,
    const unsigned short* __restrict__ bucket, const int* __restrict__ cnt,
    const int* __restrict__ ovcnt, const int* __restrict__ ovlist,
    short* __restrict__ r)
{
    int n = *ovcnt; if (n > OV_CAP) n = OV_CAP;
    int c = threadIdx.x;                      // one channel per thread
    for (int i = 0; i < n; i++) {
        int dst = ovlist[i * 2 + 1];
        bool dup = false;                     // uniform across threads
        for (int i2 = 0; i2 < i; i2++)
            if (ovlist[i2 * 2 + 1] == dst) { dup = true; break; }
        if (dup) continue;
        int m = cnt[dst]; if (m > CAP) m = CAP;
        const unsigned short* bk = bucket + (long)dst * CAP;
        float acc = 0.f;
        for (int j = 0; j < m; j++)
            acc += bf2f(h[(long)bk[j] * 128 + c]);
        for (int i2 = 0; i2 < n; i2++)
            if (ovlist[i2 * 2 + 1] == dst)
                acc += bf2f(h[(long)ovlist[i2 * 2] * 128 + c]);
        r[(long)dst * 128 + c] = f2bf(fmaxf(acc + b1[c], 0.f));
    }
}

__global__ __launch_bounds__(128) void ovfix2_k(
    const short* __restrict__ r, const unsigned short* __restrict__ bucket,
    const int* __restrict__ cnt, const int* __restrict__ ovcnt,
    const int* __restrict__ ovlist, short* __restrict__ r2)
{
    int n = *ovcnt; if (n > OV_CAP) n = OV_CAP;
    int c = threadIdx.x;
    for (int i = 0; i < n; i++) {
        int dst = ovlist[i * 2 + 1];
        bool dup = false;                     // uniform across threads
        for (int i2 = 0; i2 < i; i2++)
            if (ovlist[i2 * 2 + 1] == dst) { dup = true; break; }
        if (dup) continue;
        int m = cnt[dst]; if (m > CAP) m = CAP;
        const unsigned short* bk = bucket + (long)dst * CAP;
        float acc = 0.f;
        for (int j = 0; j < m; j++)
            acc += bf2f(r[(long)bk[j] * 128 + c]);
        for (int i2 = 0; i2 < n; i2++)
            if (ovlist[i2 * 2 + 1] == dst)
                acc += bf2f(r[(long)ovlist[i2 * 2] * 128 + c]);
        r2[(long)dst * 128 + c] = f2bf(acc);
    }
}

extern "C" void kernel_launch(void* const* d_in, const int* in_sizes, int n_in,
                              void* d_out, int out_size, void* d_ws, size_t ws_size,
                              hipStream_t stream) {
    const float* x  = (const float*)d_in[0];
    const int*   ei = (const int*)d_in[1];
    const float* w1 = (const float*)d_in[2];
    const float* b1 = (const float*)d_in[3];
    const float* w2 = (const float*)d_in[4];
    const float* b2 = (const float*)d_in[5];
    float* out = (float*)d_out;

    char* ws = (char*)d_ws;
    size_t off = 0;
    short* h    = (short*)(ws + off); off += (size_t)NN * HIDC * 2;          // 12.8 MB
    short* r    = (short*)(ws + off); off += (size_t)NN * HIDC * 2;          // 12.8 MB
    short* r2   = (short*)(ws + off); off += (size_t)NN * HIDC * 2;          // 12.8 MB
    unsigned short* bucket = (unsigned short*)(ws + off);
    off += (size_t)NN * CAP * 2;                                             // 6.4 MB
    int* cnt    = (int*)(ws + off);   off += (size_t)NN * 4;                 // 0.2 MB
    int* ovcnt  = (int*)(ws + off);   off += 256;
    int* ovlist = (int*)(ws + off);   off += (size_t)OV_CAP * 2 * 4;         // 0.5 MB

    // zero cnt + ovcnt in one memset (contiguous)
    hipMemsetAsync(cnt, 0, (size_t)NN * 4 + 4, stream);

    dim3 blk(256);

    // build buckets (blocks 0..3124, 1 edge/thread) || h = bf16(x @ w1^T)
    fat_build_gemm1<<<dim3(BUILD_BLOCKS + GB1), blk, 0, stream>>>(
        ei, cnt, bucket, ovcnt, ovlist, x, w1, h);

    // r = bf16(relu(A*h + b1))
    gather_k<true><<<dim3(3125), blk, 0, stream>>>(h, bucket, cnt, b1, r);
    ovfix1_k<<<dim3(1), dim3(128), 0, stream>>>(h, b1, bucket, cnt, ovcnt, ovlist, r);

    // r2 = bf16(A*r)
    gather_k<false><<<dim3(3125), blk, 0, stream>>>(r, bucket, cnt, nullptr, r2);
    ovfix2_k<<<dim3(1), dim3(128), 0, stream>>>(r, bucket, cnt, ovcnt, ovlist, r2);

    // out = r2 @ w2^T + b2
    gemm2_k<<<dim3(GB1, 2), blk, 0, stream>>>(r2, w2, b2, out);
}

// Round 8
// 305.226 us; speedup vs baseline: 1.1357x; 1.1357x over previous
//
#include <hip/hip_runtime.h>

#define NN 50000
#define EE 800000
#define INC 512
#define HIDC 128
#define OUTC 256
#define CAP 64
#define OV_CAP 65536
#define BUILD_BLOCKS 196      // ceil(800000 / (256*16)) — measured-best build form
#define GB1 782               // ceil(NN/64)

typedef __attribute__((ext_vector_type(8))) short bf16x8;
typedef __attribute__((ext_vector_type(4))) float f32x4;

__device__ __forceinline__ short f2bf(float f) {
    unsigned u = __float_as_uint(f);
    unsigned r = u + 0x7fff + ((u >> 16) & 1);   // RNE to bf16
    return (short)(r >> 16);
}
__device__ __forceinline__ float bf2f(short s) {
    return __uint_as_float(((unsigned)(unsigned short)s) << 16);
}

// ---------------------------------------------------------------------------
// GEMM core (layer 1 only now): C = A*B^T. BM=64, BN=128, BK=64. 4 waves,
// wave computes 32x64 (2x4 tiles of 16x16x32 MFMA). Verified layouts:
// A-frag A[m=lane&15][k=quad*8+j]; C/D col=lane&15, row=quad*4+reg.
__device__ __forceinline__ void gemm1_core(
    const float* __restrict__ A, const float* __restrict__ B,
    short* __restrict__ C, int bx,
    short As[64][72], short Bs[128][72])
{
    int tid = threadIdx.x;
    int lane = tid & 63, wave = tid >> 6;
    int row0 = bx * 64;
    int wm = (wave & 1) * 32, wn = (wave >> 1) * 64;
    int l16 = lane & 15, quad = lane >> 4;

    f32x4 acc[2][4];
#pragma unroll
    for (int i = 0; i < 2; i++)
#pragma unroll
        for (int j = 0; j < 4; j++) acc[i][j] = {0.f, 0.f, 0.f, 0.f};

    for (int k0 = 0; k0 < INC; k0 += 64) {
        // stage A tile 64x64 (fp32 -> bf16)
#pragma unroll
        for (int w = 0; w < 4; w++) {
            int f = tid + w * 256;              // 1024 x float4 slots
            int rr = f >> 4, c4 = f & 15;
            int gr = row0 + rr;
            float4 v = make_float4(0.f, 0.f, 0.f, 0.f);
            if (gr < NN) v = *(const float4*)&A[(long)gr * INC + k0 + c4 * 4];
            short4 s;
            s.x = f2bf(v.x); s.y = f2bf(v.y); s.z = f2bf(v.z); s.w = f2bf(v.w);
            *(short4*)&As[rr][c4 * 4] = s;
        }
        // stage B tile 128x64 (fp32 -> bf16)
#pragma unroll
        for (int w = 0; w < 8; w++) {
            int f = tid + w * 256;              // 2048 x float4 slots
            int rr = f >> 4, c4 = f & 15;
            float4 v = *(const float4*)&B[(long)rr * INC + k0 + c4 * 4];
            short4 s;
            s.x = f2bf(v.x); s.y = f2bf(v.y); s.z = f2bf(v.z); s.w = f2bf(v.w);
            *(short4*)&Bs[rr][c4 * 4] = s;
        }
        __syncthreads();

#pragma unroll
        for (int kk = 0; kk < 64; kk += 32) {
            bf16x8 af[2], bfr[4];
#pragma unroll
            for (int i = 0; i < 2; i++)
                af[i] = *(const bf16x8*)&As[wm + i * 16 + l16][kk + quad * 8];
#pragma unroll
            for (int j = 0; j < 4; j++)
                bfr[j] = *(const bf16x8*)&Bs[wn + j * 16 + l16][kk + quad * 8];
#pragma unroll
            for (int i = 0; i < 2; i++)
#pragma unroll
                for (int j = 0; j < 4; j++)
                    acc[i][j] = __builtin_amdgcn_mfma_f32_16x16x32_bf16(
                        af[i], bfr[j], acc[i][j], 0, 0, 0);
        }
        __syncthreads();
    }

#pragma unroll
    for (int i = 0; i < 2; i++)
#pragma unroll
        for (int rr = 0; rr < 4; rr++) {
            int grow = row0 + wm + i * 16 + quad * 4 + rr;
            if (grow < NN)
#pragma unroll
                for (int j = 0; j < 4; j++)
                    C[(long)grow * HIDC + wn + j * 16 + l16] = f2bf(acc[i][j][rr]);
        }
}

// ---------------------------------------------------------------------------
// Fat kernel: blocks [0,196) build dst-buckets at 16 edges/thread (REVERTED
// to the measured-best form: 196 blocks overlap under gemm1's MFMA blocks;
// the 1-edge/thread variant regressed 91->137us — pure atomic storm first,
// gemm1 serialized after). Remaining 782 blocks: h = bf16(x @ w1^T).
__global__ __launch_bounds__(256) void fat_build_gemm1(
    const int* __restrict__ ei, int* __restrict__ cnt,
    unsigned short* __restrict__ bucket, int* __restrict__ ovcnt,
    int* __restrict__ ovlist,
    const float* __restrict__ x, const float* __restrict__ w1,
    short* __restrict__ h)
{
    __shared__ short As[64][72];
    __shared__ short Bs[128][72];

    if (blockIdx.x < BUILD_BLOCKS) {
        int t = threadIdx.x;
        long base = ((long)blockIdx.x * 256 + t) * 16;
        if (base + 16 <= EE) {
            int4 sv[4], dv[4];
#pragma unroll
            for (int q = 0; q < 4; q++) {
                sv[q] = *(const int4*)&ei[base + q * 4];
                dv[q] = *(const int4*)&ei[EE + base + q * 4];
            }
            const int* sp = (const int*)sv;
            const int* dp = (const int*)dv;
#pragma unroll
            for (int k = 0; k < 16; k++) {
                int src = sp[k], dst = dp[k];
                int pos = atomicAdd(&cnt[dst], 1);
                if (pos < CAP) bucket[(long)dst * CAP + pos] = (unsigned short)src;
                else {
                    int o = atomicAdd(ovcnt, 1);
                    if (o < OV_CAP) { ovlist[o * 2] = src; ovlist[o * 2 + 1] = dst; }
                }
            }
        } else {
            for (int k = 0; k < 16; k++) {
                long e = base + k;
                if (e < EE) {
                    int src = ei[e], dst = ei[EE + e];
                    int pos = atomicAdd(&cnt[dst], 1);
                    if (pos < CAP) bucket[(long)dst * CAP + pos] = (unsigned short)src;
                    else {
                        int o = atomicAdd(ovcnt, 1);
                        if (o < OV_CAP) { ovlist[o * 2] = src; ovlist[o * 2 + 1] = dst; }
                    }
                }
            }
        }
    } else {
        gemm1_core(x, w1, h, blockIdx.x - BUILD_BLOCKS, As, Bs);
    }
}

// ---------------------------------------------------------------------------
// Per-node full sum incl. inline overflow handling (exact: if cnt>CAP, the
// extra srcs live in ovlist; n==0 expected so the branch is never taken).
__device__ __forceinline__ void gather_row(
    const short* __restrict__ hsrc, const unsigned short* __restrict__ bk,
    int m0, const int* __restrict__ ovcnt, const int* __restrict__ ovlist,
    int node, int c8, float acc[8])
{
#pragma unroll
    for (int k = 0; k < 8; k++) acc[k] = 0.f;
    int m = m0 > CAP ? CAP : m0;
    int j = 0;
    for (; j + 8 <= m; j += 8) {
        int s[8];
#pragma unroll
        for (int q = 0; q < 8; q++) s[q] = bk[j + q];
        bf16x8 v[8];
#pragma unroll
        for (int q = 0; q < 8; q++)
            v[q] = *(const bf16x8*)&hsrc[((long)s[q] << 7) + c8 * 8];
#pragma unroll
        for (int q = 0; q < 8; q++)
#pragma unroll
            for (int k = 0; k < 8; k++) acc[k] += bf2f(v[q][k]);
    }
    for (; j < m; j++) {
        int s0 = bk[j];
        bf16x8 v0 = *(const bf16x8*)&hsrc[((long)s0 << 7) + c8 * 8];
#pragma unroll
        for (int k = 0; k < 8; k++) acc[k] += bf2f(v0[k]);
    }
    if (m0 > CAP) {                 // overflow fixup inline (expected never)
        int n = *ovcnt; if (n > OV_CAP) n = OV_CAP;
        for (int i = 0; i < n; i++) {
            if (ovlist[i * 2 + 1] == node) {
                bf16x8 v0 = *(const bf16x8*)&hsrc[((long)ovlist[i * 2] << 7) + c8 * 8];
#pragma unroll
                for (int k = 0; k < 8; k++) acc[k] += bf2f(v0[k]);
            }
        }
    }
}

// ---------------------------------------------------------------------------
// Gather layer 1: r = bf16(relu(A*h + b1)). 16 lanes/node, overflow inline.
__global__ __launch_bounds__(256) void gather1_k(
    const short* __restrict__ h, const unsigned short* __restrict__ bucket,
    const int* __restrict__ cnt, const int* __restrict__ ovcnt,
    const int* __restrict__ ovlist, const float* __restrict__ b1,
    short* __restrict__ r)
{
    int t = threadIdx.x;
    int node = blockIdx.x * 16 + (t >> 4);
    int c8 = t & 15;
    if (node >= NN) return;
    float acc[8];
    gather_row(h, bucket + (long)node * CAP, cnt[node], ovcnt, ovlist,
               node, c8, acc);
    bf16x8 o;
#pragma unroll
    for (int k = 0; k < 8; k++)
        o[k] = f2bf(fmaxf(acc[k] + b1[c8 * 8 + k], 0.f));
    *(bf16x8*)&r[((long)node << 7) + c8 * 8] = o;
}

// ---------------------------------------------------------------------------
// Fused gather layer 2 + gemm2: block owns 64 nodes. Phase 1 gathers
// r2-rows = bf16(A*r) straight into the GEMM A-tile in LDS (identical
// numerics to the old materialized r2: bf16 RNE of the fp32 sum, then bf16
// MFMA). Phase 2: out[64,256] = As * w2^T + b2, fp32. Kills the r2
// round-trip (25.6 MB) + one launch + both ovfix launches.
__global__ __launch_bounds__(256) void fused_gather2_gemm2(
    const short* __restrict__ r, const unsigned short* __restrict__ bucket,
    const int* __restrict__ cnt, const int* __restrict__ ovcnt,
    const int* __restrict__ ovlist,
    const float* __restrict__ w2, const float* __restrict__ b2,
    float* __restrict__ out)
{
    __shared__ short As[64][136];   // [node][k], K=128, +8 shorts pad
    __shared__ short Bs[128][136];  // [outcol][k] (half of w2 per pass)

    int t = threadIdx.x;
    int lane = t & 63, wave = t >> 6;
    int grp = t >> 4, c8 = t & 15;
    int l16 = lane & 15, quad = lane >> 4;
    int row0 = blockIdx.x * 64;

    // ---- Phase 1: gather 64 rows into As (16-lane group does 4 nodes) ----
    for (int it = 0; it < 4; it++) {
        int rr = grp * 4 + it;              // 0..63
        int node = row0 + rr;
        float acc[8];
        if (node < NN) {
            gather_row(r, bucket + (long)node * CAP, cnt[node], ovcnt, ovlist,
                       node, c8, acc);
        } else {
#pragma unroll
            for (int k = 0; k < 8; k++) acc[k] = 0.f;
        }
        bf16x8 o;
#pragma unroll
        for (int k = 0; k < 8; k++) o[k] = f2bf(acc[k]);
        *(bf16x8*)&As[rr][c8 * 8] = o;
    }
    __syncthreads();

    // ---- Phase 2: C = As[64,128] * w2^T (+b2), two 128-col halves ----
    int wm = (wave & 1) * 32, wn = (wave >> 1) * 64;
#pragma unroll
    for (int by = 0; by < 2; by++) {
        // stage Bs: 128 rows x 128 k, fp32 -> bf16 (4096 float4 slots)
#pragma unroll
        for (int w = 0; w < 16; w++) {
            int f = t + w * 256;
            int rr = f >> 5, c4 = f & 31;
            float4 v = *(const float4*)&w2[(long)(by * 128 + rr) * HIDC + c4 * 4];
            short4 s;
            s.x = f2bf(v.x); s.y = f2bf(v.y); s.z = f2bf(v.z); s.w = f2bf(v.w);
            *(short4*)&Bs[rr][c4 * 4] = s;
        }
        __syncthreads();

        f32x4 acc[2][4];
#pragma unroll
        for (int i = 0; i < 2; i++)
#pragma unroll
            for (int j = 0; j < 4; j++) acc[i][j] = {0.f, 0.f, 0.f, 0.f};

#pragma unroll
        for (int kk = 0; kk < 128; kk += 32) {
            bf16x8 af[2], bfr[4];
#pragma unroll
            for (int i = 0; i < 2; i++)
                af[i] = *(const bf16x8*)&As[wm + i * 16 + l16][kk + quad * 8];
#pragma unroll
            for (int j = 0; j < 4; j++)
                bfr[j] = *(const bf16x8*)&Bs[wn + j * 16 + l16][kk + quad * 8];
#pragma unroll
            for (int i = 0; i < 2; i++)
#pragma unroll
                for (int j = 0; j < 4; j++)
                    acc[i][j] = __builtin_amdgcn_mfma_f32_16x16x32_bf16(
                        af[i], bfr[j], acc[i][j], 0, 0, 0);
        }

#pragma unroll
        for (int i = 0; i < 2; i++)
#pragma unroll
            for (int rr = 0; rr < 4; rr++) {
                int grow = row0 + wm + i * 16 + quad * 4 + rr;
                if (grow < NN)
#pragma unroll
                    for (int j = 0; j < 4; j++) {
                        int gcol = by * 128 + wn + j * 16 + l16;
                        out[(long)grow * OUTC + gcol] = acc[i][j][rr] + b2[gcol];
                    }
            }
        __syncthreads();   // all waves done reading Bs before restage
    }
}

extern "C" void kernel_launch(void* const* d_in, const int* in_sizes, int n_in,
                              void* d_out, int out_size, void* d_ws, size_t ws_size,
                              hipStream_t stream) {
    const float* x  = (const float*)d_in[0];
    const int*   ei = (const int*)d_in[1];
    const float* w1 = (const float*)d_in[2];
    const float* b1 = (const float*)d_in[3];
    const float* w2 = (const float*)d_in[4];
    const float* b2 = (const float*)d_in[5];
    float* out = (float*)d_out;

    char* ws = (char*)d_ws;
    size_t off = 0;
    short* h    = (short*)(ws + off); off += (size_t)NN * HIDC * 2;          // 12.8 MB
    short* r    = (short*)(ws + off); off += (size_t)NN * HIDC * 2;          // 12.8 MB
    unsigned short* bucket = (unsigned short*)(ws + off);
    off += (size_t)NN * CAP * 2;                                             // 6.4 MB
    int* cnt    = (int*)(ws + off);   off += (size_t)NN * 4;                 // 0.2 MB
    int* ovcnt  = (int*)(ws + off);   off += 256;
    int* ovlist = (int*)(ws + off);   off += (size_t)OV_CAP * 2 * 4;         // 0.5 MB

    // zero cnt + ovcnt in one memset (contiguous)
    hipMemsetAsync(cnt, 0, (size_t)NN * 4 + 4, stream);

    dim3 blk(256);

    // build buckets (blocks 0..195) || h = bf16(x @ w1^T) (blocks 196..977)
    fat_build_gemm1<<<dim3(BUILD_BLOCKS + GB1), blk, 0, stream>>>(
        ei, cnt, bucket, ovcnt, ovlist, x, w1, h);

    // r = bf16(relu(A*h + b1)), overflow inline
    gather1_k<<<dim3(3125), blk, 0, stream>>>(h, bucket, cnt, ovcnt, ovlist, b1, r);

    // out = (A*r) @ w2^T + b2, gather fused into GEMM A-tile, overflow inline
    fused_gather2_gemm2<<<dim3(GB1), blk, 0, stream>>>(
        r, bucket, cnt, ovcnt, ovlist, w2, b2, out);
}